// Round 10
// baseline (55.327 us; speedup 1.0000x reference)
//
#include <hip/hip_runtime.h>

// DynamicKoopmanOperator — R10: R9 + vectorized ksplit-reduce + 2-chain rollout.
// R9 confirmed: MLP was operand-issue bound; W @16B/instr on VMEM fixed it
// (16.5 -> ~6.5us). Remaining: store phase ~44us @6.1 TB/s vs fill's 7.08.
// This round: (1) f32x4 LDS reduce (4x fewer DS instrs in the serial MLP
// segment); (2) two independent T-quarter chains per wave -> 2 independent
// 1 KiB stores/iter (isolates the store-ILP hypothesis; R5's apparent 2-chain
// win was confounded with an MLP change).

#define DT_CONST 0.01f

typedef float f32x4 __attribute__((ext_vector_type(4)));

constexpr int KDIM   = 256;
constexpr int AROWS  = 4;               // batch rows per block -> 256 blocks
constexpr int KSPLIT = 8;               // k-slices (= wave id)
constexpr int KSLICE = KDIM / KSPLIT;   // 32 k's per slice

// ---------------- fused kernel ----------------------------------------------
__global__ __launch_bounds__(512) void koopman_fused(
    const float* __restrict__ x,  const float* __restrict__ W1,
    const float* __restrict__ b1, const float* __restrict__ W2,
    const float* __restrict__ b2, float* __restrict__ out, int T)
{
    __shared__ alignas(16) float xs[AROWS][KDIM];              // 4 KiB
    __shared__ alignas(16) float hs[AROWS][KDIM];              // 4 KiB
    __shared__ alignas(16) float coef[AROWS][KDIM];            // 4 KiB
    __shared__ alignas(16) float part[KSPLIT][AROWS][KDIM];    // 32 KiB

    const int tid = threadIdx.x;
    const int jg  = tid & 63;           // column group: cols [jg*4, jg*4+4)
    const int ks  = tid >> 6;           // k-slice 0..7 (wave-uniform)
    const int b0  = blockIdx.x * AROWS;

    // stage x rows (vectorized, 256 f32x4)
    {
        const f32x4* xg = reinterpret_cast<const f32x4*>(x + (size_t)b0 * KDIM);
        f32x4* xl = reinterpret_cast<f32x4*>(&xs[0][0]);
        for (int i = tid; i < AROWS * KDIM / 4; i += 512) xl[i] = xg[i];
    }
    __syncthreads();

    f32x4 acc[AROWS];

    // ---- GEMM 1: h = tanh(x @ W1 + b1) ----
    {
#pragma unroll
        for (int r = 0; r < AROWS; ++r) acc[r] = (f32x4){0.f, 0.f, 0.f, 0.f};
        const float* wbase = W1 + (size_t)ks * KSLICE * KDIM + jg * 4;
#pragma unroll 2
        for (int k4 = 0; k4 < KSLICE / 4; ++k4) {
            f32x4 wv[4];
#pragma unroll
            for (int i = 0; i < 4; ++i)      // 4x global dwordx4, coalesced
                wv[i] = *reinterpret_cast<const f32x4*>(wbase + (size_t)(k4 * 4 + i) * KDIM);
            f32x4 xv[AROWS];
#pragma unroll
            for (int r = 0; r < AROWS; ++r)  // uniform b128 broadcast
                xv[r] = *reinterpret_cast<const f32x4*>(&xs[r][ks * KSLICE + k4 * 4]);
#pragma unroll
            for (int i = 0; i < 4; ++i)
#pragma unroll
                for (int r = 0; r < AROWS; ++r)
                    acc[r] += wv[i] * xv[r][i];      // vec FMA
        }
#pragma unroll
        for (int r = 0; r < AROWS; ++r)
            *reinterpret_cast<f32x4*>(&part[ks][r][jg * 4]) = acc[r];
    }
    __syncthreads();
    // reduce ksplit partials + bias + tanh -> hs  (vectorized: f32x4 per thread)
    if (tid < AROWS * KDIM / 4) {
        const int r = tid >> 6, j4 = tid & 63;
        f32x4 ssum = *reinterpret_cast<const f32x4*>(b1 + j4 * 4);
#pragma unroll
        for (int s = 0; s < KSPLIT; ++s)
            ssum += *reinterpret_cast<const f32x4*>(&part[s][r][j4 * 4]);
        f32x4 hv = { tanhf(ssum.x), tanhf(ssum.y), tanhf(ssum.z), tanhf(ssum.w) };
        *reinterpret_cast<f32x4*>(&hs[r][j4 * 4]) = hv;
    }
    __syncthreads();

    // ---- GEMM 2: eigs = h @ W2 + b2 ----
    {
#pragma unroll
        for (int r = 0; r < AROWS; ++r) acc[r] = (f32x4){0.f, 0.f, 0.f, 0.f};
        const float* wbase = W2 + (size_t)ks * KSLICE * KDIM + jg * 4;
#pragma unroll 2
        for (int k4 = 0; k4 < KSLICE / 4; ++k4) {
            f32x4 wv[4];
#pragma unroll
            for (int i = 0; i < 4; ++i)
                wv[i] = *reinterpret_cast<const f32x4*>(wbase + (size_t)(k4 * 4 + i) * KDIM);
            f32x4 hv[AROWS];
#pragma unroll
            for (int r = 0; r < AROWS; ++r)
                hv[r] = *reinterpret_cast<const f32x4*>(&hs[r][ks * KSLICE + k4 * 4]);
#pragma unroll
            for (int i = 0; i < 4; ++i)
#pragma unroll
                for (int r = 0; r < AROWS; ++r)
                    acc[r] += wv[i] * hv[r][i];
        }
#pragma unroll
        for (int r = 0; r < AROWS; ++r)
            *reinterpret_cast<f32x4*>(&part[ks][r][jg * 4]) = acc[r];
    }
    __syncthreads();
    // reduce + bias, pre-scale by dt -> coef (vectorized)
    if (tid < AROWS * KDIM / 4) {
        const int r = tid >> 6, j4 = tid & 63;
        f32x4 ssum = *reinterpret_cast<const f32x4*>(b2 + j4 * 4);
#pragma unroll
        for (int s = 0; s < KSPLIT; ++s)
            ssum += *reinterpret_cast<const f32x4*>(&part[s][r][j4 * 4]);
        *reinterpret_cast<f32x4*>(&coef[r][j4 * 4]) = ssum * DT_CONST;
    }
    __syncthreads();

    // ---- Phase 2: rollout. wave -> row r, TWO T-quarter chains ----
    const int wave = tid >> 6;
    const int lane = tid & 63;              // lane = 2 pairs (4 elems)
    const int r    = wave & (AROWS - 1);    // row within block
    const int th   = wave >> 2;             // 0/1
    const int b    = b0 + r;
    const int tlen = (T + 3) >> 2;          // 64
    const int t0A  = th * tlen;             // quarters th and th+2
    const int t0B  = (th + 2) * tlen;

    const f32x4 c  = *reinterpret_cast<const f32x4*>(&coef[r][lane * 4]);
    const f32x4 xv = *reinterpret_cast<const f32x4*>(&xs[r][lane * 4]);
    // c = (mu0*dt, om0*dt, mu1*dt, om1*dt)

    float s, co, e;
    // per-step multipliers (shared by both chains — same row)
    e = expf(c.x); sincosf(c.y, &s, &co);
    const float a0 = e * co, g0 = e * s;
    e = expf(c.z); sincosf(c.w, &s, &co);
    const float a1 = e * co, g1 = e * s;

    // seed chain A at t0A
    const float tfA = (float)t0A;
    e = expf(c.x * tfA); sincosf(c.y * tfA, &s, &co);
    float zA0 = e * (co * xv.x - s * xv.y), zA1 = e * (s * xv.x + co * xv.y);
    e = expf(c.z * tfA); sincosf(c.w * tfA, &s, &co);
    float zA2 = e * (co * xv.z - s * xv.w), zA3 = e * (s * xv.z + co * xv.w);
    // seed chain B at t0B
    const float tfB = (float)t0B;
    e = expf(c.x * tfB); sincosf(c.y * tfB, &s, &co);
    float zB0 = e * (co * xv.x - s * xv.y), zB1 = e * (s * xv.x + co * xv.y);
    e = expf(c.z * tfB); sincosf(c.w * tfB, &s, &co);
    float zB2 = e * (co * xv.z - s * xv.w), zB3 = e * (s * xv.z + co * xv.w);

    f32x4* oA = reinterpret_cast<f32x4*>(out + ((size_t)b * T + t0A) * KDIM) + lane;
    f32x4* oB = reinterpret_cast<f32x4*>(out + ((size_t)b * T + t0B) * KDIM) + lane;
    const int ntA = (t0A + tlen < T) ? tlen : (T - t0A > 0 ? T - t0A : 0);
    const int ntB = (t0B + tlen < T) ? tlen : (T - t0B > 0 ? T - t0B : 0);
#pragma unroll 4
    for (int t = 0; t < tlen; ++t) {
        float nA0 = a0 * zA0 - g0 * zA1;
        float nA1 = g0 * zA0 + a0 * zA1;
        float nA2 = a1 * zA2 - g1 * zA3;
        float nA3 = g1 * zA2 + a1 * zA3;
        float nB0 = a0 * zB0 - g0 * zB1;
        float nB1 = g0 * zB0 + a0 * zB1;
        float nB2 = a1 * zB2 - g1 * zB3;
        float nB3 = g1 * zB2 + a1 * zB3;
        if (t < ntA) {                        // wave-uniform branch (cheap)
            f32x4 vA = { nA0, nA1, nA2, nA3 };
            *oA = vA; oA += KDIM / 4;
        }
        if (t < ntB) {
            f32x4 vB = { nB0, nB1, nB2, nB3 };
            *oB = vB; oB += KDIM / 4;
        }
        zA0 = nA0; zA1 = nA1; zA2 = nA2; zA3 = nA3;
        zB0 = nB0; zB1 = nB1; zB2 = nB2; zB3 = nB3;
    }
}

// ---------------- launcher ---------------------------------------------------
extern "C" void kernel_launch(void* const* d_in, const int* in_sizes, int n_in,
                              void* d_out, int out_size, void* d_ws, size_t ws_size,
                              hipStream_t stream) {
    const float* x  = (const float*)d_in[0];
    const float* W1 = (const float*)d_in[1];
    const float* b1 = (const float*)d_in[2];
    const float* W2 = (const float*)d_in[3];
    const float* b2 = (const float*)d_in[4];

    const int Kd = in_sizes[2];                 // 256
    const int Bb = in_sizes[0] / Kd;            // 1024
    const int T  = out_size / (Bb * Kd);        // 256

    float* out = (float*)d_out;

    koopman_fused<<<Bb / AROWS, 512, 0, stream>>>(x, W1, b1, W2, b2, out, T);
}

// Round 11
// 52.425 us; speedup vs baseline: 1.0554x; 1.0554x over previous
//
#include <hip/hip_runtime.h>

// DynamicKoopmanOperator — R11: R9 (proven 52.4us) + f32x4 ksplit-reduce only.
// R10's 2-chain rollout REGRESSED (+3.5us): store-ILP hypothesis refuted —
// fill hits 7 TB/s at 3.4 waves/CU, store queue never starved; the second
// dependent stream per wave only added VALU/branch overhead. Reverted.
// Kept: vectorized reduce (DS cycles halved: 8192 b32 -> 2048 b128 per CU).
//
// Decomposition: launch ~1.5 + MLP ~6.5 (L2 floor 3.7) + store ~44 @ 5.9 TB/s
// (fill ceiling 7.08 -> floor 37.9). Composite floor ~43-46us.

#define DT_CONST 0.01f

typedef float f32x4 __attribute__((ext_vector_type(4)));

constexpr int KDIM   = 256;
constexpr int AROWS  = 4;               // batch rows per block -> 256 blocks
constexpr int KSPLIT = 8;               // k-slices (= wave id)
constexpr int KSLICE = KDIM / KSPLIT;   // 32 k's per slice

// ---------------- fused kernel ----------------------------------------------
__global__ __launch_bounds__(512) void koopman_fused(
    const float* __restrict__ x,  const float* __restrict__ W1,
    const float* __restrict__ b1, const float* __restrict__ W2,
    const float* __restrict__ b2, float* __restrict__ out, int T)
{
    __shared__ alignas(16) float xs[AROWS][KDIM];              // 4 KiB
    __shared__ alignas(16) float hs[AROWS][KDIM];              // 4 KiB
    __shared__ alignas(16) float coef[AROWS][KDIM];            // 4 KiB
    __shared__ alignas(16) float part[KSPLIT][AROWS][KDIM];    // 32 KiB

    const int tid = threadIdx.x;
    const int jg  = tid & 63;           // column group: cols [jg*4, jg*4+4)
    const int ks  = tid >> 6;           // k-slice 0..7 (wave-uniform)
    const int b0  = blockIdx.x * AROWS;

    // stage x rows (vectorized, 256 f32x4)
    {
        const f32x4* xg = reinterpret_cast<const f32x4*>(x + (size_t)b0 * KDIM);
        f32x4* xl = reinterpret_cast<f32x4*>(&xs[0][0]);
        for (int i = tid; i < AROWS * KDIM / 4; i += 512) xl[i] = xg[i];
    }
    __syncthreads();

    f32x4 acc[AROWS];

    // ---- GEMM 1: h = tanh(x @ W1 + b1) ----
    {
#pragma unroll
        for (int r = 0; r < AROWS; ++r) acc[r] = (f32x4){0.f, 0.f, 0.f, 0.f};
        const float* wbase = W1 + (size_t)ks * KSLICE * KDIM + jg * 4;
#pragma unroll 2
        for (int k4 = 0; k4 < KSLICE / 4; ++k4) {
            f32x4 wv[4];
#pragma unroll
            for (int i = 0; i < 4; ++i)      // 4x global dwordx4, coalesced
                wv[i] = *reinterpret_cast<const f32x4*>(wbase + (size_t)(k4 * 4 + i) * KDIM);
            f32x4 xv[AROWS];
#pragma unroll
            for (int r = 0; r < AROWS; ++r)  // uniform b128 broadcast
                xv[r] = *reinterpret_cast<const f32x4*>(&xs[r][ks * KSLICE + k4 * 4]);
#pragma unroll
            for (int i = 0; i < 4; ++i)
#pragma unroll
                for (int r = 0; r < AROWS; ++r)
                    acc[r] += wv[i] * xv[r][i];      // vec FMA
        }
#pragma unroll
        for (int r = 0; r < AROWS; ++r)
            *reinterpret_cast<f32x4*>(&part[ks][r][jg * 4]) = acc[r];
    }
    __syncthreads();
    // reduce ksplit partials + bias + tanh -> hs  (f32x4: 2048 b128 reads/CU)
    if (tid < AROWS * KDIM / 4) {
        const int r = tid >> 6, j4 = tid & 63;
        f32x4 ssum = *reinterpret_cast<const f32x4*>(b1 + j4 * 4);
#pragma unroll
        for (int s = 0; s < KSPLIT; ++s)
            ssum += *reinterpret_cast<const f32x4*>(&part[s][r][j4 * 4]);
        f32x4 hv = { tanhf(ssum.x), tanhf(ssum.y), tanhf(ssum.z), tanhf(ssum.w) };
        *reinterpret_cast<f32x4*>(&hs[r][j4 * 4]) = hv;
    }
    __syncthreads();

    // ---- GEMM 2: eigs = h @ W2 + b2 ----
    {
#pragma unroll
        for (int r = 0; r < AROWS; ++r) acc[r] = (f32x4){0.f, 0.f, 0.f, 0.f};
        const float* wbase = W2 + (size_t)ks * KSLICE * KDIM + jg * 4;
#pragma unroll 2
        for (int k4 = 0; k4 < KSLICE / 4; ++k4) {
            f32x4 wv[4];
#pragma unroll
            for (int i = 0; i < 4; ++i)
                wv[i] = *reinterpret_cast<const f32x4*>(wbase + (size_t)(k4 * 4 + i) * KDIM);
            f32x4 hv[AROWS];
#pragma unroll
            for (int r = 0; r < AROWS; ++r)
                hv[r] = *reinterpret_cast<const f32x4*>(&hs[r][ks * KSLICE + k4 * 4]);
#pragma unroll
            for (int i = 0; i < 4; ++i)
#pragma unroll
                for (int r = 0; r < AROWS; ++r)
                    acc[r] += wv[i] * hv[r][i];
        }
#pragma unroll
        for (int r = 0; r < AROWS; ++r)
            *reinterpret_cast<f32x4*>(&part[ks][r][jg * 4]) = acc[r];
    }
    __syncthreads();
    // reduce + bias, pre-scale by dt -> coef (f32x4)
    if (tid < AROWS * KDIM / 4) {
        const int r = tid >> 6, j4 = tid & 63;
        f32x4 ssum = *reinterpret_cast<const f32x4*>(b2 + j4 * 4);
#pragma unroll
        for (int s = 0; s < KSPLIT; ++s)
            ssum += *reinterpret_cast<const f32x4*>(&part[s][r][j4 * 4]);
        *reinterpret_cast<f32x4*>(&coef[r][j4 * 4]) = ssum * DT_CONST;
    }
    __syncthreads();

    // ---- Phase 2: rollout (R9's proven single chain per wave) ----
    const int wave = tid >> 6;
    const int lane = tid & 63;              // lane = 2 pairs (4 elems)
    const int r    = wave & (AROWS - 1);    // row within block
    const int tseg = wave >> 2;             // 0/1
    const int b    = b0 + r;
    const int tlen = (T + 1) >> 1;          // 128
    const int t0   = tseg * tlen;

    const f32x4 c  = *reinterpret_cast<const f32x4*>(&coef[r][lane * 4]);
    const f32x4 xv = *reinterpret_cast<const f32x4*>(&xs[r][lane * 4]);
    // c = (mu0*dt, om0*dt, mu1*dt, om1*dt)

    const float tf = (float)t0;
    float s, co, e;
    e = expf(c.x * tf); sincosf(c.y * tf, &s, &co);
    float z0 = e * (co * xv.x - s * xv.y);
    float z1 = e * (s * xv.x + co * xv.y);
    e = expf(c.z * tf); sincosf(c.w * tf, &s, &co);
    float z2 = e * (co * xv.z - s * xv.w);
    float z3 = e * (s * xv.z + co * xv.w);

    e = expf(c.x); sincosf(c.y, &s, &co);
    const float a0 = e * co, g0 = e * s;
    e = expf(c.z); sincosf(c.w, &s, &co);
    const float a1 = e * co, g1 = e * s;

    f32x4* orow = reinterpret_cast<f32x4*>(out + ((size_t)b * T + t0) * KDIM) + lane;
    const int nt = ((t0 + tlen < T) ? tlen : (T - t0));
#pragma unroll 4
    for (int t = 0; t < nt; ++t) {
        float n0 = a0 * z0 - g0 * z1;
        float n1 = g0 * z0 + a0 * z1;
        float n2 = a1 * z2 - g1 * z3;
        float n3 = g1 * z2 + a1 * z3;
        f32x4 v = { n0, n1, n2, n3 };
        *orow = v;                           // plain store, through L2
        orow += KDIM / 4;                    // next timestep, 1 KiB row/wave
        z0 = n0; z1 = n1; z2 = n2; z3 = n3;
    }
}

// ---------------- launcher ---------------------------------------------------
extern "C" void kernel_launch(void* const* d_in, const int* in_sizes, int n_in,
                              void* d_out, int out_size, void* d_ws, size_t ws_size,
                              hipStream_t stream) {
    const float* x  = (const float*)d_in[0];
    const float* W1 = (const float*)d_in[1];
    const float* b1 = (const float*)d_in[2];
    const float* W2 = (const float*)d_in[3];
    const float* b2 = (const float*)d_in[4];

    const int Kd = in_sizes[2];                 // 256
    const int Bb = in_sizes[0] / Kd;            // 1024
    const int T  = out_size / (Bb * Kd);        // 256

    float* out = (float*)d_out;

    koopman_fused<<<Bb / AROWS, 512, 0, stream>>>(x, W1, b1, W2, b2, out, T);
}